// Round 3
// baseline (2563.956 us; speedup 1.0000x reference)
//
#include <hip/hip_runtime.h>
#include <hip/hip_bf16.h>

// LSTM: B=256, T=2048, D=64, U=64. fp32.
// One workgroup per batch element (256 WGs = 1 per CU, 4 waves/CU).
// Thread g owns gate column g (i:[0,64) f:[64,128) g:[128,192) o:[192,256)).
// Weight columns in registers (asm-pinned). Input vec [x_t ; h] in LDS.
// R2 lesson: step time 2250 cyc vs 615 cyc VALU -> stall-bound. Fixes:
//  - raw s_barrier (lgkmcnt(0) only, NO vmcnt drain) instead of __syncthreads
//  - x prefetch distance 2 (two rotating regs, loop unrolled x2)
//  - state update replicated in all 4 waves; output stores split across waves

#define LSTM_B 256
#define LSTM_T 2048
#define LSTM_D 64
#define LSTM_U 64
#define LSTM_G 256   // 4*U

__device__ __forceinline__ float fast_sigmoid(float z) {
    return 1.0f / (1.0f + __expf(-z));
}

__device__ __forceinline__ float fast_tanh(float z) {
    float az = fabsf(z);
    float e = __expf(-2.0f * az);          // in (0,1], no overflow
    float t = (1.0f - e) / (1.0f + e);
    return copysignf(t, z);
}

// Workgroup barrier that orders LDS ops but does NOT drain vmcnt:
// global stores / x-prefetch loads stay in flight across it.
__device__ __forceinline__ void sync_lds() {
    __builtin_amdgcn_sched_barrier(0);
    asm volatile("s_waitcnt lgkmcnt(0)" ::: "memory");
    __builtin_amdgcn_sched_barrier(0);
    __builtin_amdgcn_s_barrier();
    __builtin_amdgcn_sched_barrier(0);
}

__global__ __launch_bounds__(256, 1)
void lstm_seq_kernel(const float* __restrict__ x,
                     const float* __restrict__ Wx,
                     const float* __restrict__ Wh,
                     const float* __restrict__ bias,
                     float* __restrict__ out)
{
    const int batch = blockIdx.x;
    const int g = threadIdx.x;            // gate column 0..255
    const int u = g & 63;                 // unit index
    const int wv = g >> 6;                // wave id 0..3

    // ---- weight column into registers: w[0:64)=Wx[:,g], w[64:128)=Wh[:,g] ----
    float w[2 * LSTM_U];
#pragma unroll
    for (int d = 0; d < LSTM_D; ++d) {
        w[d] = Wx[d * LSTM_G + g];
        asm volatile("" : "+v"(w[d]));    // pin: forbid remat/sink into t-loop
    }
#pragma unroll
    for (int k = 0; k < LSTM_U; ++k) {
        w[LSTM_U + k] = Wh[k * LSTM_G + g];
        asm volatile("" : "+v"(w[LSTM_U + k]));
    }
    const float b = bias[g];

    __shared__ __align__(16) float sIn[2 * LSTM_U];   // [0:64) x_t, [64:128) h
    __shared__ __align__(16) float sAct[LSTM_G];

    const float* xb = x + (size_t)batch * LSTM_T * LSTM_D;
    float* ob = out + (size_t)batch * LSTM_T * (2 * LSTM_U);

    // replicated cell state: every wave's lane u holds c_u
    float c = 0.0f;

    // init LDS: x_0 and h=0
    if (g < 128) sIn[g] = (g < 64) ? xb[g] : 0.0f;

    // wave2 holds the x prefetch pipeline (distance 2)
    float r0 = 0.0f, r1 = 0.0f;
    if (wv == 2) {
        r0 = xb[(size_t)1 * LSTM_D + u];  // x_1
        r1 = xb[(size_t)2 * LSTM_D + u];  // x_2
    }

    __syncthreads();

    auto substep = [&](int t, float& xr) {
        // ---- phase 1: z_g = b + [x_t;h] . w  (LDS broadcast reads) ----
        float a0 = 0.f, a1 = 0.f, a2 = 0.f, a3 = 0.f;
#pragma unroll
        for (int k = 0; k < 2 * LSTM_U; k += 4) {
            float4 v = *(const float4*)&sIn[k];
            a0 = fmaf(v.x, w[k + 0], a0);
            a1 = fmaf(v.y, w[k + 1], a1);
            a2 = fmaf(v.z, w[k + 2], a2);
            a3 = fmaf(v.w, w[k + 3], a3);
        }
        float z = b + ((a0 + a1) + (a2 + a3));
        // candidate gate (wave2's columns) -> tanh, others sigmoid (wave-uniform)
        float act = (wv == 2) ? fast_tanh(z) : fast_sigmoid(z);
        sAct[g] = act;
        sync_lds();                                        // B1: sAct ready

        // ---- phase 2: replicated state update (all waves) ----
        float i_g = sAct[u];
        float f_g = sAct[u + 64];
        float g_g = sAct[u + 128];
        float o_g = sAct[u + 192];
        c = fmaf(f_g, c, i_g * g_g);
        float h = o_g * fast_tanh(c);

        if (wv == 0) {
            ob[(size_t)t * 128 + u] = c;                   // cell state
        } else if (wv == 3) {
            ob[(size_t)t * 128 + 64 + u] = h;              // hidden state
        } else if (wv == 1) {
            sIn[LSTM_U + u] = h;                           // publish h
        } else { // wv == 2
            sIn[u] = xr;                                   // publish x_{t+1}
            int idx = (t + 3 < LSTM_T) ? (t + 3) : 0;      // guard tail
            xr = xb[(size_t)idx * LSTM_D + u];             // prefetch dist 2
        }
        sync_lds();                                        // B2: sIn ready
    };

    for (int t = 0; t < LSTM_T; t += 2) {
        substep(t, r0);
        substep(t + 1, r1);
    }
}

extern "C" void kernel_launch(void* const* d_in, const int* in_sizes, int n_in,
                              void* d_out, int out_size, void* d_ws, size_t ws_size,
                              hipStream_t stream) {
    const float* x  = (const float*)d_in[0];
    const float* Wx = (const float*)d_in[1];
    const float* Wh = (const float*)d_in[2];
    const float* b  = (const float*)d_in[3];
    float* out = (float*)d_out;

    hipLaunchKernelGGL(lstm_seq_kernel, dim3(LSTM_B), dim3(LSTM_G), 0, stream,
                       x, Wx, Wh, b, out);
}

// Round 4
// 2456.271 us; speedup vs baseline: 1.0438x; 1.0438x over previous
//
#include <hip/hip_runtime.h>

// LSTM: B=256, T=2048, D=64, U=64, fp32.
// 1 workgroup (256 thr) per batch element = 1 WG/CU, 1 wave/SIMD.
// Thread (wv,u): wave wv in {i,f,g,o}, computes gate column g = wv*64+u.
// R3 lesson: LDS broadcast reads of [x;h] (128 b128/CU/step) were the floor
// (~1200+ cyc/step LDS pipe). Fix: operands delivered via v_readlane from
// lane-resident x_t / h (zero LDS in the dot product). Weights in 8x f32x16
// ext-vectors, waves_per_eu(1,1) for the full 512-VGPR budget.

#define LSTM_T 2048
#define LSTM_D 64
#define LSTM_U 64
#define LSTM_G 256

typedef float f32x16 __attribute__((ext_vector_type(16)));

__device__ __forceinline__ float rlane(float v, int l) {
    return __int_as_float(__builtin_amdgcn_readlane(__float_as_int(v), l));
}

__device__ __forceinline__ float fast_sigmoid(float z) {
    return 1.0f / (1.0f + __expf(-z));
}

__device__ __forceinline__ float fast_tanh(float z) {
    float az = fabsf(z);
    float e = __expf(-2.0f * az);          // in (0,1], no overflow
    float t = (1.0f - e) / (1.0f + e);
    return copysignf(t, z);
}

// Barrier ordering LDS only — never drains vmcnt (global stores/loads fly on).
__device__ __forceinline__ void sync_lds() {
    __builtin_amdgcn_sched_barrier(0);
    asm volatile("s_waitcnt lgkmcnt(0)" ::: "memory");
    __builtin_amdgcn_sched_barrier(0);
    __builtin_amdgcn_s_barrier();
    __builtin_amdgcn_sched_barrier(0);
}

__global__ __attribute__((amdgpu_flat_work_group_size(256, 256),
                          amdgpu_waves_per_eu(1, 1)))
void lstm_seq_kernel(const float* __restrict__ x,
                     const float* __restrict__ Wx,
                     const float* __restrict__ Wh,
                     const float* __restrict__ bias,
                     float* __restrict__ out)
{
    const int batch = blockIdx.x;
    const int tid = threadIdx.x;
    const int u  = tid & 63;     // unit / lane
    const int wv = tid >> 6;     // gate: 0=i 1=f 2=g(cand) 3=o

    // ---- weight column g=tid in 8 x f32x16: W[0..3]=Wx[:,g], W[4..7]=Wh[:,g]
    f32x16 W[8];
#pragma unroll
    for (int j = 0; j < 4; ++j) {
#pragma unroll
        for (int e = 0; e < 16; ++e) {
            W[j][e]     = Wx[(j * 16 + e) * LSTM_G + tid];
            W[4 + j][e] = Wh[(j * 16 + e) * LSTM_G + tid];
        }
    }
#pragma unroll
    for (int j = 0; j < 8; ++j) asm volatile("" : "+v"(W[j]));  // pin tuples
    const float b = bias[tid];

    // gate exchange: double-buffered, stride 5 (conflict-free both ways)
    __shared__ float sAct[2][5 * LSTM_U];

    const float* xb = x + (size_t)batch * LSTM_T * LSTM_D;
    float* ob = out + (size_t)batch * LSTM_T * (2 * LSTM_U);

    float h = 0.0f, c = 0.0f;
    // lane-resident x pipeline (each wave keeps its own copy; L1 dedups)
    float xcur = xb[u];                       // x[0]
    float xr0  = xb[LSTM_D + u];              // x[1]
    float xr1  = xb[2 * LSTM_D + u];          // x[2]

    auto substep = [&](int t, int p, float& xnxt) {
        // ---- z = b + x_t . Wx[:,g] + h . Wh[:,g] via readlane broadcast ----
        float a0 = b, a1 = 0.f, a2 = 0.f, a3 = 0.f;
#pragma unroll
        for (int k = 0; k < LSTM_D; k += 4) {
            a0 = fmaf(rlane(xcur, k + 0), W[k >> 4][(k + 0) & 15], a0);
            a1 = fmaf(rlane(xcur, k + 1), W[k >> 4][(k + 1) & 15], a1);
            a2 = fmaf(rlane(xcur, k + 2), W[k >> 4][(k + 2) & 15], a2);
            a3 = fmaf(rlane(xcur, k + 3), W[k >> 4][(k + 3) & 15], a3);
        }
#pragma unroll
        for (int k = 0; k < LSTM_U; k += 4) {
            a0 = fmaf(rlane(h, k + 0), W[4 + (k >> 4)][(k + 0) & 15], a0);
            a1 = fmaf(rlane(h, k + 1), W[4 + (k >> 4)][(k + 1) & 15], a1);
            a2 = fmaf(rlane(h, k + 2), W[4 + (k >> 4)][(k + 2) & 15], a2);
            a3 = fmaf(rlane(h, k + 3), W[4 + (k >> 4)][(k + 3) & 15], a3);
        }
        float z = (a0 + a1) + (a2 + a3);
        float act = (wv == 2) ? fast_tanh(z) : fast_sigmoid(z);
        sAct[p][u * 5 + wv] = act;
        sync_lds();                                        // the ONLY barrier

        // ---- replicated state update: every wave's lane u owns (c_u,h_u) ----
        float i_g = sAct[p][u * 5 + 0];
        float f_g = sAct[p][u * 5 + 1];
        float g_g = sAct[p][u * 5 + 2];
        float o_g = sAct[p][u * 5 + 3];
        c = fmaf(f_g, c, i_g * g_g);
        h = o_g * fast_tanh(c);

        if (wv == 0)      ob[(size_t)t * 128 + u]      = c;   // cell state
        else if (wv == 1) ob[(size_t)t * 128 + 64 + u] = h;   // hidden state

        // rotate x pipeline (prefetch distance 2, vmcnt never drained)
        xcur = xnxt;
        int idx = (t + 3 < LSTM_T) ? (t + 3) : 0;
        xnxt = xb[(size_t)idx * LSTM_D + u];
    };

    for (int t = 0; t < LSTM_T; t += 2) {
        substep(t,     0, xr0);
        substep(t + 1, 1, xr1);
    }
}

extern "C" void kernel_launch(void* const* d_in, const int* in_sizes, int n_in,
                              void* d_out, int out_size, void* d_ws, size_t ws_size,
                              hipStream_t stream) {
    const float* x  = (const float*)d_in[0];
    const float* Wx = (const float*)d_in[1];
    const float* Wh = (const float*)d_in[2];
    const float* b  = (const float*)d_in[3];
    float* out = (float*)d_out;

    hipLaunchKernelGGL(lstm_seq_kernel, dim3(256), dim3(LSTM_G), 0, stream,
                       x, Wx, Wh, b, out);
}

// Round 5
// 2334.867 us; speedup vs baseline: 1.0981x; 1.0520x over previous
//
#include <hip/hip_runtime.h>

// LSTM: B=256, T=2048, D=64, U=64, fp32.
// 512 threads per batch element (1 WG/CU, 8 waves, 2 per SIMD).
// Split-K: tid<256 -> x.Wx[:,col] partial (64 wts), tid>=256 -> h.Wh[:,col]
// partial (64 wts). 64 weights/thread fits VGPRs BY CONSTRUCTION (R4 lesson:
// 128/thread forced AGPR spills, +128 VALU/step accvgpr reads).
// h broadcast via readlane from replicated lane-resident state; x via
// broadcast float4 loads. 2 lgkm-only barriers/step; vmcnt never drained.

#define LSTM_T 2048
#define LSTM_D 64
#define LSTM_U 64
#define LSTM_G 256

__device__ __forceinline__ float rlane(float v, int l) {
    return __int_as_float(__builtin_amdgcn_readlane(__float_as_int(v), l));
}

__device__ __forceinline__ float fast_sigmoid(float z) {
    return 1.0f / (1.0f + __expf(-z));
}

__device__ __forceinline__ float fast_tanh(float z) {
    float az = fabsf(z);
    float e = __expf(-2.0f * az);          // in (0,1], no overflow
    float t = (1.0f - e) / (1.0f + e);
    return copysignf(t, z);
}

// Workgroup barrier ordering LDS only — does NOT drain vmcnt, so global
// stores and x loads stay in flight across it.
__device__ __forceinline__ void sync_lds() {
    __builtin_amdgcn_sched_barrier(0);
    asm volatile("s_waitcnt lgkmcnt(0)" ::: "memory");
    __builtin_amdgcn_sched_barrier(0);
    __builtin_amdgcn_s_barrier();
    __builtin_amdgcn_sched_barrier(0);
}

__global__ __launch_bounds__(512, 2)
void lstm_seq_kernel(const float* __restrict__ x,
                     const float* __restrict__ Wx,
                     const float* __restrict__ Wh,
                     const float* __restrict__ bias,
                     float* __restrict__ out)
{
    const int batch = blockIdx.x;
    const int tid = threadIdx.x;
    const int col = tid & 255;          // gate column
    const int u   = tid & 63;           // unit
    const int wv  = (tid >> 6) & 3;     // gate index within half: 0=i 1=f 2=g 3=o
    const bool xhalf = (tid < 256);

    // 64-float weight column (x-half: Wx[:,col]; h-half: Wh[:,col])
    const float* Wp = xhalf ? Wx : Wh;
    float w[64];
#pragma unroll
    for (int k = 0; k < 64; ++k) {
        w[k] = Wp[k * LSTM_G + col];
        asm volatile("" : "+v"(w[k]));  // keep resident across the t-loop
    }
    const float b = bias[col];

    __shared__ __align__(16) float sPart[256];     // h-half partials
    __shared__ __align__(16) float sAct[64 * 6];   // gates, stride 6 (f2-aligned)

    const float* xb = x + (size_t)batch * LSTM_T * LSTM_D;
    float* ob = out + (size_t)batch * LSTM_T * (2 * LSTM_U);

    // replicated state: every thread's lane u holds (c_u, h_u)
    float h = 0.0f, c = 0.0f;

    for (int t = 0; t < LSTM_T; ++t) {
        float a0, a1, a2, a3;
        if (xhalf) {
            // a = b + x_t . Wx[:,col] ; x_t via broadcast float4 loads (L1-hit)
            a0 = b; a1 = 0.f; a2 = 0.f; a3 = 0.f;
            const float* xt = xb + (size_t)t * LSTM_D;
#pragma unroll
            for (int k = 0; k < LSTM_D; k += 4) {
                float4 v = *(const float4*)&xt[k];
                a0 = fmaf(v.x, w[k + 0], a0);
                a1 = fmaf(v.y, w[k + 1], a1);
                a2 = fmaf(v.z, w[k + 2], a2);
                a3 = fmaf(v.w, w[k + 3], a3);
            }
        } else {
            // a = h . Wh[:,col] via readlane broadcast of lane-resident h
            a0 = 0.f; a1 = 0.f; a2 = 0.f; a3 = 0.f;
#pragma unroll
            for (int k = 0; k < LSTM_U; k += 4) {
                a0 = fmaf(rlane(h, k + 0), w[k + 0], a0);
                a1 = fmaf(rlane(h, k + 1), w[k + 1], a1);
                a2 = fmaf(rlane(h, k + 2), w[k + 2], a2);
                a3 = fmaf(rlane(h, k + 3), w[k + 3], a3);
            }
            sPart[col] = ((a0 + a1) + (a2 + a3));
        }
        sync_lds();                                    // B1: sPart ready

        if (xhalf) {
            float z = ((a0 + a1) + (a2 + a3)) + sPart[col];
            float act = (wv == 2) ? fast_tanh(z) : fast_sigmoid(z);
            sAct[u * 6 + wv] = act;
        }
        sync_lds();                                    // B2: sAct ready

        // replicated state update (all 8 waves)
        float2 if_ = *(const float2*)&sAct[u * 6];     // (i, f)
        float2 go_ = *(const float2*)&sAct[u * 6 + 2]; // (g, o)
        c = fmaf(if_.y, c, if_.x * go_.x);
        h = go_.y * fast_tanh(c);

        if (tid < 64)                    ob[(size_t)t * 128 + u]      = c;
        else if (tid >= 256 && tid < 320) ob[(size_t)t * 128 + 64 + u] = h;
    }
}

extern "C" void kernel_launch(void* const* d_in, const int* in_sizes, int n_in,
                              void* d_out, int out_size, void* d_ws, size_t ws_size,
                              hipStream_t stream) {
    const float* x  = (const float*)d_in[0];
    const float* Wx = (const float*)d_in[1];
    const float* Wh = (const float*)d_in[2];
    const float* b  = (const float*)d_in[3];
    float* out = (float*)d_out;

    hipLaunchKernelGGL(lstm_seq_kernel, dim3(256), dim3(512), 0, stream,
                       x, Wx, Wh, b, out);
}

// Round 6
// 1199.767 us; speedup vs baseline: 2.1370x; 1.9461x over previous
//
#include <hip/hip_runtime.h>
#include <stdint.h>

// LSTM B=256,T=2048,D=U=64 fp32. 256 WGs (1 batch each) x 512 thr (8 waves).
// R1-R5 lesson: per-step weight operand delivery is the wall (131KB/CU/step
// from L1/L2 ~= 2000cyc). Fix: weights live in LDS as f16 (64KB total),
// consumed via v_dot2_f32_f16 (2 MAC/inst, f32 accum).
// Wave specialization: waves 0-3 = recurrence (h.Wh + gates + state),
// waves 4-7 = producers precomputing xz = x.Wx + b one 16-step chunk ahead
// into LDS ping-pong. Gate exchange intra-wave via shfl_xor (lane = q*16+i
// so all 4 gates of unit u are in one wave). One lgkm-only barrier per step.

#define T_STEPS 2048
#define DIM     64
#define GATES   256
#define CHUNK   16
#define NCHUNK  (T_STEPS / CHUNK)

typedef _Float16 f16;
typedef _Float16 f16x2 __attribute__((ext_vector_type(2)));

__device__ __forceinline__ float fdot2u(uint32_t a, uint32_t b, float acc) {
    return __builtin_amdgcn_fdot2(__builtin_bit_cast(f16x2, a),
                                  __builtin_bit_cast(f16x2, b), acc, false);
}

// Barrier ordering LDS only — never drains vmcnt (stores/loads stay in flight)
__device__ __forceinline__ void sync_lds() {
    __builtin_amdgcn_sched_barrier(0);
    asm volatile("s_waitcnt lgkmcnt(0)" ::: "memory");
    __builtin_amdgcn_sched_barrier(0);
    __builtin_amdgcn_s_barrier();
    __builtin_amdgcn_sched_barrier(0);
}

// select A[m] from {A0..A3}
__device__ __forceinline__ float pick4(int m, float A0, float A1, float A2, float A3) {
    float r  = (m & 1) ? A1 : A0;
    float sx = (m & 1) ? A3 : A2;
    return (m & 2) ? sx : r;
}

__global__ __launch_bounds__(512, 2)
void lstm_pc_kernel(const float* __restrict__ x,
                    const float* __restrict__ Wx,
                    const float* __restrict__ Wh,
                    const float* __restrict__ bias,
                    float* __restrict__ out)
{
    // f16 weights, row = 64 f16 = 32 dwords; 16B chunks XOR-swizzled by col&7
    __shared__ uint32_t sWh[GATES * 32];          // 32 KB
    __shared__ uint32_t sWx[GATES * 32];          // 32 KB
    __shared__ float    sXZ[2][CHUNK][GATES];     // 32 KB  xz ping-pong
    __shared__ uint32_t sX [2][CHUNK * 32];       // 8 KB   x chunks (f16)
    __shared__ uint32_t sH [2][32];               // 512 B  h vector (f16), dbuf

    const int tid = threadIdx.x;
    const int batch = blockIdx.x;
    const float* xb = x + (size_t)batch * T_STEPS * DIM;
    float* ob = out + (size_t)batch * T_STEPS * (2 * DIM);

    // ---------------- prologue: weights -> LDS (f16, swizzled) -------------
    {
        const int col = tid & 255;
        const int kb  = (tid >> 8) * 32;
        f16* wxr = (f16*)&sWx[col * 32];
        f16* whr = (f16*)&sWh[col * 32];
#pragma unroll
        for (int kk = 0; kk < 32; ++kk) {
            int k = kb + kk;
            int fi = (((k >> 3) ^ (col & 7)) << 3) | (k & 7);  // swizzled f16 idx
            wxr[fi] = (f16)Wx[k * GATES + col];
            whr[fi] = (f16)Wh[k * GATES + col];
        }
    }
    if (tid < 64) { ((f16*)sH[0])[tid] = (f16)0.f; ((f16*)sH[1])[tid] = (f16)0.f; }
    if (tid >= 256) {                       // x chunks 0,1 -> sX[0],sX[1]
        const int p = tid - 256;
#pragma unroll
        for (int j = 0; j < 8; ++j) {
            int v = p + 256 * j;            // flat idx into first 2 chunks
            ((f16*)sX[v >> 10])[v & 1023] = (f16)xb[v];
        }
    }
    __syncthreads();

    if (tid >= 256) {                       // xz chunk 0 (producers)
        const int pcol = tid & 255;
        const int pc7  = pcol & 7;
        const float bc = bias[pcol];
#pragma unroll 1
        for (int s2 = 0; s2 < CHUNK; ++s2) {
            float a0 = bc, a1 = 0.f, a2 = 0.f, a3 = 0.f;
            const uint32_t* xr = &sX[0][s2 * 32];
#pragma unroll
            for (int j = 0; j < 8; ++j) {
                uint4 wq = *(const uint4*)&sWx[pcol * 32 + ((j ^ pc7) << 2)];
                uint4 xq = *(const uint4*)&xr[j << 2];
                a0 = fdot2u(wq.x, xq.x, a0);
                a1 = fdot2u(wq.y, xq.y, a1);
                a2 = fdot2u(wq.z, xq.z, a2);
                a3 = fdot2u(wq.w, xq.w, a3);
            }
            sXZ[0][s2][pcol] = (a0 + a1) + (a2 + a3);
        }
    }
    __syncthreads();

    if (tid < 256) {
        // ============================ CONSUMER ============================
        const int lane = tid & 63;
        const int w    = tid >> 6;          // wave 0..3 -> units w*16..+16
        const int q    = lane >> 4;         // gate 0=i 1=f 2=g 3=o
        const int i    = lane & 15;
        const int u    = w * 16 + i;
        const int col  = q * 64 + u;
        const int c7   = col & 7;
        float c = 0.f;
#pragma unroll 1
        for (int t = 0; t < T_STEPS; ++t) {
            const int p  = t & 1;
            const int cb = (t >> 4) & 1;
            const int s  = t & 15;
            float a0 = 0.f, a1 = 0.f, a2 = 0.f, a3 = 0.f;
#pragma unroll
            for (int j = 0; j < 8; ++j) {
                uint4 wq = *(const uint4*)&sWh[col * 32 + ((j ^ c7) << 2)];
                uint4 hq = *(const uint4*)&sH[p][j << 2];     // broadcast
                a0 = fdot2u(wq.x, hq.x, a0);
                a1 = fdot2u(wq.y, hq.y, a1);
                a2 = fdot2u(wq.z, hq.z, a2);
                a3 = fdot2u(wq.w, hq.w, a3);
            }
            float z = ((a0 + a1) + (a2 + a3)) + sXZ[cb][s][col];
            // one exp path: tanh(z) = 2*sigmoid(2z)-1 (inf-safe)
            float zz  = (q == 2) ? (z + z) : z;
            float e   = __expf(-zz);
            float sg  = 1.0f / (1.0f + e);
            float act = (q == 2) ? fmaf(2.f, sg, -1.f) : sg;
            // intra-wave gate exchange: lane set {l, l^16, l^32, l^48}
            float A1 = __shfl_xor(act, 16, 64);
            float A2 = __shfl_xor(act, 32, 64);
            float A3 = __shfl_xor(A2, 16, 64);
            float gI = pick4(q,     act, A1, A2, A3);
            float gF = pick4(1 ^ q, act, A1, A2, A3);
            float gG = pick4(2 ^ q, act, A1, A2, A3);
            float gO = pick4(3 ^ q, act, A1, A2, A3);
            c = fmaf(gF, c, gI * gG);
            float ac = fabsf(c);
            float e2 = __expf(-2.f * ac);
            float th = copysignf((1.f - e2) / (1.f + e2), c);
            float h  = gO * th;
            if (q == 0)      ob[(size_t)t * 128 + u]      = c;   // cell
            else if (q == 1) ob[(size_t)t * 128 + 64 + u] = h;   // hidden
            else if (q == 2) ((f16*)sH[p ^ 1])[u] = (f16)h;      // next-step h
            sync_lds();
        }
    } else {
        // ============================ PRODUCER ============================
        const int pcol = tid & 255;
        const int pc7  = pcol & 7;
        const int pidx = tid - 256;
        const float bc = bias[pcol];
        float xs0 = 0.f, xs1 = 0.f, xs2 = 0.f, xs3 = 0.f;
#pragma unroll 1
        for (int t = 0; t < T_STEPS; ++t) {
            const int n = t >> 4;
            const int s = t & 15;
            if (n + 1 < NCHUNK) {           // xz row for chunk n+1, step s
                const int nb = (n + 1) & 1;
                float a0 = bc, a1 = 0.f, a2 = 0.f, a3 = 0.f;
                const uint32_t* xr = &sX[nb][s * 32];
#pragma unroll
                for (int j = 0; j < 8; ++j) {
                    uint4 wq = *(const uint4*)&sWx[pcol * 32 + ((j ^ pc7) << 2)];
                    uint4 xq = *(const uint4*)&xr[j << 2];
                    a0 = fdot2u(wq.x, xq.x, a0);
                    a1 = fdot2u(wq.y, xq.y, a1);
                    a2 = fdot2u(wq.z, xq.z, a2);
                    a3 = fdot2u(wq.w, xq.w, a3);
                }
                sXZ[nb][s][pcol] = (a0 + a1) + (a2 + a3);
            }
            if (n + 2 < NCHUNK) {           // stage x for chunk n+2
                const float* xsrc = xb + (size_t)(n + 2) * CHUNK * DIM;
                if (s == 0) {               // issue loads (latency hidden)
                    xs0 = xsrc[pidx];
                    xs1 = xsrc[pidx + 256];
                    xs2 = xsrc[pidx + 512];
                    xs3 = xsrc[pidx + 768];
                }
                if (s == 8) {               // write f16 half a chunk later
                    f16* dst = (f16*)sX[n & 1];
                    dst[pidx]       = (f16)xs0;
                    dst[pidx + 256] = (f16)xs1;
                    dst[pidx + 512] = (f16)xs2;
                    dst[pidx + 768] = (f16)xs3;
                }
            }
            sync_lds();
        }
    }
}

extern "C" void kernel_launch(void* const* d_in, const int* in_sizes, int n_in,
                              void* d_out, int out_size, void* d_ws, size_t ws_size,
                              hipStream_t stream) {
    const float* x  = (const float*)d_in[0];
    const float* Wx = (const float*)d_in[1];
    const float* Wh = (const float*)d_in[2];
    const float* b  = (const float*)d_in[3];
    float* out = (float*)d_out;

    hipLaunchKernelGGL(lstm_pc_kernel, dim3(256), dim3(512), 0, stream,
                       x, Wx, Wh, b, out);
}

// Round 7
// 882.849 us; speedup vs baseline: 2.9042x; 1.3590x over previous
//
#include <hip/hip_runtime.h>
#include <stdint.h>

// LSTM B=256,T=2048,D=U=64 fp32. 256 WGs (1 batch each) x 512 thr (8 waves).
// R6 lesson: LDS weight re-read (64KB/CU/step) + miskeyed swizzle (1.4e8 bank
// conflicts) was the wall. R7: weights live in REGISTERS as 32 x f16x2 per
// thread (half R5's footprint), consumed by v_dot2_f32_f16. LDS holds only
// broadcast vectors: sH (256B, dbuf), sX chunks, sXZ ping-pong.
// Waves 0-3 consumers (h.Wh + gates + state), waves 4-7 producers (xz=x.Wx+b
// one 16-step chunk ahead). One lgkm-only barrier per step (vmcnt never
// drained). Gate exchange intra-wave via 3x shfl_xor.

#define T_STEPS 2048
#define DIM     64
#define GATES   256
#define CHUNK   16
#define NCHUNK  (T_STEPS / CHUNK)

typedef _Float16 f16;
typedef _Float16 f16x2 __attribute__((ext_vector_type(2)));

__device__ __forceinline__ float fdot2u(uint32_t a, uint32_t b, float acc) {
    return __builtin_amdgcn_fdot2(__builtin_bit_cast(f16x2, a),
                                  __builtin_bit_cast(f16x2, b), acc, false);
}

__device__ __forceinline__ uint32_t packh(float lo, float hi) {
    f16x2 v; v.x = (f16)lo; v.y = (f16)hi;
    return __builtin_bit_cast(uint32_t, v);
}

// Barrier ordering LDS only — never drains vmcnt (stores/loads stay in flight)
__device__ __forceinline__ void sync_lds() {
    __builtin_amdgcn_sched_barrier(0);
    asm volatile("s_waitcnt lgkmcnt(0)" ::: "memory");
    __builtin_amdgcn_sched_barrier(0);
    __builtin_amdgcn_s_barrier();
    __builtin_amdgcn_sched_barrier(0);
}

// select A[m] from {A0..A3}
__device__ __forceinline__ float pick4(int m, float A0, float A1, float A2, float A3) {
    float r  = (m & 1) ? A1 : A0;
    float sx = (m & 1) ? A3 : A2;
    return (m & 2) ? sx : r;
}

__global__ __launch_bounds__(512, 2)
void lstm_reg_kernel(const float* __restrict__ x,
                     const float* __restrict__ Wx,
                     const float* __restrict__ Wh,
                     const float* __restrict__ bias,
                     float* __restrict__ out)
{
    __shared__ float    sXZ[2][CHUNK][GATES];     // 32 KB  xz ping-pong
    __shared__ uint32_t sX [2][CHUNK * 32];       // 8 KB   x chunks (f16)
    __shared__ uint32_t sH [2][32];               // 256 B  h vector (f16), dbuf

    const int tid = threadIdx.x;
    const int batch = blockIdx.x;
    const float* xb = x + (size_t)batch * T_STEPS * DIM;
    float* ob = out + (size_t)batch * T_STEPS * (2 * DIM);

    const int lane = tid & 63;
    const int wv   = (tid >> 6) & 3;      // wave within half
    const int q    = lane >> 4;           // gate 0=i 1=f 2=g 3=o (consumer)
    const int i    = lane & 15;
    const int u    = wv * 16 + i;         // unit (consumer)
    const bool consumer = (tid < 256);
    // consumer col = q*64+u (gate-major); producer col = tid&255
    const int wcol = consumer ? (q * 64 + u) : (tid & 255);

    // ---- weight column in 32 f16x2 registers ----
    const float* Wsrc = consumer ? Wh : Wx;
    uint32_t w[32];
#pragma unroll
    for (int jj = 0; jj < 32; ++jj)
        w[jj] = packh(Wsrc[(2 * jj) * GATES + wcol],
                      Wsrc[(2 * jj + 1) * GATES + wcol]);
#pragma unroll
    for (int jj = 0; jj < 32; ++jj) asm volatile("" : "+v"(w[jj]));
    const float bc = bias[wcol];          // used by producers only

    // ---- prologue: h=0, stage x chunks 0,1; xz chunk 0 ----
    if (tid < 32) { sH[0][tid] = 0u; sH[1][tid] = 0u; }
    if (!consumer) {
        const int p = tid - 256;
#pragma unroll
        for (int j = 0; j < 8; ++j) {
            int v = p + 256 * j;          // flat f16 idx into first 2 chunks
            ((f16*)sX[v >> 10])[v & 1023] = (f16)xb[v];
        }
    }
    __syncthreads();
    if (!consumer) {                      // xz chunk 0
#pragma unroll 1
        for (int s2 = 0; s2 < CHUNK; ++s2) {
            float a0 = bc, a1 = 0.f, a2 = 0.f, a3 = 0.f;
            const uint32_t* xr = &sX[0][s2 * 32];
#pragma unroll
            for (int j = 0; j < 8; ++j) {
                uint4 xq = *(const uint4*)&xr[j << 2];
                a0 = fdot2u(w[4 * j + 0], xq.x, a0);
                a1 = fdot2u(w[4 * j + 1], xq.y, a1);
                a2 = fdot2u(w[4 * j + 2], xq.z, a2);
                a3 = fdot2u(w[4 * j + 3], xq.w, a3);
            }
            sXZ[0][s2][wcol] = (a0 + a1) + (a2 + a3);
        }
    }
    __syncthreads();

    if (consumer) {
        // ============================ CONSUMER ============================
        float c = 0.f;
#pragma unroll 1
        for (int t = 0; t < T_STEPS; ++t) {
            const int p  = t & 1;
            const int cb = (t >> 4) & 1;
            const int s  = t & 15;
            float a0 = 0.f, a1 = 0.f, a2 = 0.f, a3 = 0.f;
#pragma unroll
            for (int j = 0; j < 8; ++j) {
                uint4 hq = *(const uint4*)&sH[p][j << 2];   // broadcast
                a0 = fdot2u(w[4 * j + 0], hq.x, a0);
                a1 = fdot2u(w[4 * j + 1], hq.y, a1);
                a2 = fdot2u(w[4 * j + 2], hq.z, a2);
                a3 = fdot2u(w[4 * j + 3], hq.w, a3);
            }
            float z = ((a0 + a1) + (a2 + a3)) + sXZ[cb][s][wcol];
            // one exp path: tanh(z) = 2*sigmoid(2z)-1 (inf-safe)
            float zz  = (q == 2) ? (z + z) : z;
            float e   = __expf(-zz);
            float sg  = 1.0f / (1.0f + e);
            float act = (q == 2) ? fmaf(2.f, sg, -1.f) : sg;
            // intra-wave gate exchange: lane set {l, l^16, l^32, l^48}
            float A1 = __shfl_xor(act, 16, 64);
            float A2 = __shfl_xor(act, 32, 64);
            float A3 = __shfl_xor(A2, 16, 64);
            float gI = pick4(q,     act, A1, A2, A3);
            float gF = pick4(1 ^ q, act, A1, A2, A3);
            float gG = pick4(2 ^ q, act, A1, A2, A3);
            float gO = pick4(3 ^ q, act, A1, A2, A3);
            c = fmaf(gF, c, gI * gG);
            float ac = fabsf(c);
            float e2 = __expf(-2.f * ac);
            float th = copysignf((1.f - e2) / (1.f + e2), c);
            float h  = gO * th;
            if (q == 0)      ob[(size_t)t * 128 + u]      = c;   // cell
            else if (q == 1) ob[(size_t)t * 128 + 64 + u] = h;   // hidden
            else if (q == 2) ((f16*)sH[p ^ 1])[u] = (f16)h;      // next h
            sync_lds();
        }
    } else {
        // ============================ PRODUCER ============================
        const int pidx = tid - 256;
        float xs0 = 0.f, xs1 = 0.f, xs2 = 0.f, xs3 = 0.f;
#pragma unroll 1
        for (int t = 0; t < T_STEPS; ++t) {
            const int n = t >> 4;
            const int s = t & 15;
            if (n + 1 < NCHUNK) {           // xz row for chunk n+1, step s
                const int nb = (n + 1) & 1;
                float a0 = bc, a1 = 0.f, a2 = 0.f, a3 = 0.f;
                const uint32_t* xr = &sX[nb][s * 32];
#pragma unroll
                for (int j = 0; j < 8; ++j) {
                    uint4 xq = *(const uint4*)&xr[j << 2];
                    a0 = fdot2u(w[4 * j + 0], xq.x, a0);
                    a1 = fdot2u(w[4 * j + 1], xq.y, a1);
                    a2 = fdot2u(w[4 * j + 2], xq.z, a2);
                    a3 = fdot2u(w[4 * j + 3], xq.w, a3);
                }
                sXZ[nb][s][wcol] = (a0 + a1) + (a2 + a3);
            }
            if (n + 2 < NCHUNK) {           // stage x for chunk n+2
                const float* xsrc = xb + (size_t)(n + 2) * CHUNK * DIM;
                if (s == 0) {               // issue loads (latency hidden)
                    xs0 = xsrc[pidx];
                    xs1 = xsrc[pidx + 256];
                    xs2 = xsrc[pidx + 512];
                    xs3 = xsrc[pidx + 768];
                }
                if (s == 8) {               // write f16 half a chunk later
                    f16* dst = (f16*)sX[n & 1];
                    dst[pidx]       = (f16)xs0;
                    dst[pidx + 256] = (f16)xs1;
                    dst[pidx + 512] = (f16)xs2;
                    dst[pidx + 768] = (f16)xs3;
                }
            }
            sync_lds();
        }
    }
}

extern "C" void kernel_launch(void* const* d_in, const int* in_sizes, int n_in,
                              void* d_out, int out_size, void* d_ws, size_t ws_size,
                              hipStream_t stream) {
    const float* x  = (const float*)d_in[0];
    const float* Wx = (const float*)d_in[1];
    const float* Wh = (const float*)d_in[2];
    const float* b  = (const float*)d_in[3];
    float* out = (float*)d_out;

    hipLaunchKernelGGL(lstm_reg_kernel, dim3(256), dim3(512), 0, stream,
                       x, Wx, Wh, b, out);
}